// Round 3
// baseline (369.764 us; speedup 1.0000x reference)
//
#include <hip/hip_runtime.h>
#include <math.h>

#define EPS 1e-5f
#define SCALE 0.17677669529663687f   // 1/sqrt(32)

// packed bf16 weight offsets in d_ws (ushort units)
#define OFF_We  0
#define OFF_Wf  16384
#define OFF_Wq  24576
#define OFF_Wk  40960
#define OFF_Wv  57344
#define OFF_Wo  73728
#define OFF_Wc1 90112
#define PACK_TOTAL 98304

typedef __bf16 bf16x8 __attribute__((ext_vector_type(8)));
typedef float f32x4 __attribute__((ext_vector_type(4)));
typedef unsigned short ushort_t;
typedef unsigned short ushortx4 __attribute__((ext_vector_type(4)));

__device__ __forceinline__ ushort_t f2bf(float x) {
    unsigned u = __builtin_bit_cast(unsigned, x);
    u = (u + 0x7fffu + ((u >> 16) & 1u)) >> 16;   // RNE
    return (ushort_t)u;
}
__device__ __forceinline__ float bf2f(ushort_t v) {
    unsigned u = ((unsigned)v) << 16;
    return __builtin_bit_cast(float, u);
}

// 16-lane (DPP-row) all-lanes sum via row_ror butterfly — VALU pipe, no LDS.
#define DPPADD(x, ctrl) \
    ((x) + __builtin_bit_cast(float, __builtin_amdgcn_update_dpp( \
        __builtin_bit_cast(int, (x)), __builtin_bit_cast(int, (x)), (ctrl), 0xF, 0xF, false)))

__device__ __forceinline__ float rowsum16(float x) {
    x = DPPADD(x, 0x121);   // row_ror:1
    x = DPPADD(x, 0x122);   // row_ror:2
    x = DPPADD(x, 0x124);   // row_ror:4
    x = DPPADD(x, 0x128);   // row_ror:8
    return x;
}

// tanh-form GELU via sigmoid + HW exp; |err| <= ~4e-4 vs exact erf GELU
__device__ __forceinline__ float gelu_fast(float x) {
    float x2 = x * x;
    float u = x * fmaf(0.07135481283f, x2, 1.5957691216f);
    float e = __expf(-u);
    return x * __builtin_amdgcn_rcpf(1.0f + e);
}

// ---------------- weight pack kernel (verified r2) ----------------
__global__ __launch_bounds__(256) void pack_all(
    const float* __restrict__ We, const float* __restrict__ Wf,
    const float* __restrict__ Wq, const float* __restrict__ Wk,
    const float* __restrict__ Wv, const float* __restrict__ Wo,
    const float* __restrict__ Wc1, ushort_t* __restrict__ ws)
{
    int o = blockIdx.x * 256 + threadIdx.x;
    if (o >= PACK_TOTAL) return;
    const float* W; int K, N, base;
    if (o < OFF_Wf)        { W = We;  K = 128; N = 128; base = OFF_We; }
    else if (o < OFF_Wq)   { W = Wf;  K = 64;  N = 128; base = OFF_Wf; }
    else if (o < OFF_Wk)   { W = Wq;  K = 128; N = 128; base = OFF_Wq; }
    else if (o < OFF_Wv)   { W = Wk;  K = 128; N = 128; base = OFF_Wk; }
    else if (o < OFF_Wo)   { W = Wv;  K = 128; N = 128; base = OFF_Wv; }
    else if (o < OFF_Wc1)  { W = Wo;  K = 128; N = 128; base = OFF_Wo; }
    else                   { W = Wc1; K = 128; N = 64;  base = OFF_Wc1; }
    int e = o - base;
    int j = e & 7, l = (e >> 3) & 63, rest = e >> 9;
    int KS = K >> 5;
    int s = rest % KS, t = rest / KS;
    int k = s * 32 + ((l >> 4) << 3) + j;
    int n = (t << 4) + (l & 15);
    ws[o] = f2bf(W[k * N + n]);
}

// ---------------- GEMM helpers (layouts verified r2) ----------------
template<int KS>
__device__ __forceinline__ void load_af(bf16x8 af[2][KS], const ushort_t* A,
                                        int strideA, int lane)
{
    const int quad = lane >> 4, l16 = lane & 15;
    #pragma unroll
    for (int mt = 0; mt < 2; ++mt)
        #pragma unroll
        for (int ks = 0; ks < KS; ++ks)
            af[mt][ks] = *(const bf16x8*)(A + (mt * 16 + l16) * strideA + ks * 32 + quad * 8);
}

template<int KS, int NTN>
__device__ __forceinline__ void gemm_wf(const bf16x8 af[2][KS],
    const ushort_t* __restrict__ Wp, const float* bias8, int nt0,
    float acc[2][NTN][4], int lane)
{
    #pragma unroll
    for (int t = 0; t < NTN; ++t) {
        float b = bias8[nt0 + t];
        f32x4 a0 = {b, b, b, b}, a1 = {b, b, b, b};
        const ushort_t* bp = Wp + (size_t)(nt0 + t) * KS * 512 + lane * 8;
        #pragma unroll
        for (int ks = 0; ks < KS; ++ks) {
            bf16x8 bb = *(const bf16x8*)(bp + ks * 512);
            a0 = __builtin_amdgcn_mfma_f32_16x16x32_bf16(af[0][ks], bb, a0, 0, 0, 0);
            a1 = __builtin_amdgcn_mfma_f32_16x16x32_bf16(af[1][ks], bb, a1, 0, 0, 0);
        }
        #pragma unroll
        for (int r = 0; r < 4; ++r) { acc[0][t][r] = a0[r]; acc[1][t][r] = a1[r]; }
    }
}

// ---------------- main kernel: barrier-free, wave-private 32 rows ----------------
__global__ __launch_bounds__(128, 2) void fusion_wave(
    const float* __restrict__ eeg, const float* __restrict__ fmri,
    const float* __restrict__ be, const float* __restrict__ ge, const float* __restrict__ bge,
    const float* __restrict__ bfb, const float* __restrict__ gf, const float* __restrict__ bgf,
    const float* __restrict__ bq, const float* __restrict__ bk, const float* __restrict__ bv,
    const float* __restrict__ bo,
    const float* __restrict__ fusion_logits, const float* __restrict__ temperature,
    const float* __restrict__ bc1, const float* __restrict__ gc, const float* __restrict__ bgc,
    const float* __restrict__ Wc2, const float* __restrict__ bc2,
    const ushort_t* __restrict__ ws, float* __restrict__ out)
{
    // per-wave private buffers: stride 136 ushorts = 272B = 17*16B (b128-aligned, 2-way banks)
    __shared__ __align__(16) ushort_t B1[2][32 * 136];   // eeg raw -> ep -> ctx -> fused
    __shared__ __align__(16) ushort_t B2[2][32 * 136];   // fmri raw (stride 72) -> fp

    const int tid = threadIdx.x;
    const int wave = tid >> 6, lane = tid & 63;
    const int quad = lane >> 4, l16 = lane & 15;
    const int rowbase = blockIdx.x * 64 + wave * 32;
    ushort_t* b1 = B1[wave];
    ushort_t* b2 = B2[wave];

    // ---- stage raw inputs -> bf16 A-layout LDS (wave-private, no barrier) ----
    {
        const float4* src = (const float4*)(eeg + (size_t)rowbase * 128);
        #pragma unroll
        for (int i = 0; i < 16; ++i) {
            int idx = i * 64 + lane;
            float4 v = src[idx];
            int r = idx >> 5, k4 = (idx & 31) * 4;
            *(ushortx4*)&b1[r * 136 + k4] =
                (ushortx4){f2bf(v.x), f2bf(v.y), f2bf(v.z), f2bf(v.w)};
        }
        const float4* srcf = (const float4*)(fmri + (size_t)rowbase * 64);
        #pragma unroll
        for (int i = 0; i < 8; ++i) {
            int idx = i * 64 + lane;
            float4 v = srcf[idx];
            int r = idx >> 4, k4 = (idx & 15) * 4;
            *(ushortx4*)&b2[r * 72 + k4] =
                (ushortx4){f2bf(v.x), f2bf(v.y), f2bf(v.z), f2bf(v.w)};
        }
    }

    float accA[2][8][4];      // generic C-layout accumulator: [mtile][ntile][reg]
    float bias8[8];
    float meanS[2][4], rstdS[2][4];

    // ---- eeg @ We + be ; LN ; GELU -> ep (bf16 into b1) ----
    {
        bf16x8 af[2][4];
        load_af<4>(af, b1, 136, lane);
        #pragma unroll
        for (int nt = 0; nt < 8; ++nt) bias8[nt] = be[nt * 16 + l16];
        gemm_wf<4, 8>(af, ws + OFF_We, bias8, 0, accA, lane);
    }
    #pragma unroll
    for (int mt = 0; mt < 2; ++mt)
    #pragma unroll
    for (int r = 0; r < 4; ++r) {
        float s = 0.f, ss = 0.f;
        #pragma unroll
        for (int nt = 0; nt < 8; ++nt) { float x = accA[mt][nt][r]; s += x; ss = fmaf(x, x, ss); }
        s = rowsum16(s); ss = rowsum16(ss);
        float m = s * (1.f / 128.f);
        meanS[mt][r] = m;
        rstdS[mt][r] = rsqrtf(ss * (1.f / 128.f) - m * m + EPS);
    }
    #pragma unroll
    for (int nt = 0; nt < 8; ++nt) {
        float g = ge[nt * 16 + l16], bb = bge[nt * 16 + l16];
        #pragma unroll
        for (int mt = 0; mt < 2; ++mt)
        #pragma unroll
        for (int r = 0; r < 4; ++r) {
            float x = (accA[mt][nt][r] - meanS[mt][r]) * rstdS[mt][r] * g + bb;
            b1[(mt * 16 + quad * 4 + r) * 136 + nt * 16 + l16] = f2bf(gelu_fast(x));
        }
    }

    // ---- fmri @ Wf + bf ; LN ; GELU -> fp (bf16 into b2, stride 136) ----
    {
        bf16x8 af[2][2];
        load_af<2>(af, b2, 72, lane);
        #pragma unroll
        for (int nt = 0; nt < 8; ++nt) bias8[nt] = bfb[nt * 16 + l16];
        gemm_wf<2, 8>(af, ws + OFF_Wf, bias8, 0, accA, lane);
    }
    #pragma unroll
    for (int mt = 0; mt < 2; ++mt)
    #pragma unroll
    for (int r = 0; r < 4; ++r) {
        float s = 0.f, ss = 0.f;
        #pragma unroll
        for (int nt = 0; nt < 8; ++nt) { float x = accA[mt][nt][r]; s += x; ss = fmaf(x, x, ss); }
        s = rowsum16(s); ss = rowsum16(ss);
        float m = s * (1.f / 128.f);
        meanS[mt][r] = m;
        rstdS[mt][r] = rsqrtf(ss * (1.f / 128.f) - m * m + EPS);
    }
    #pragma unroll
    for (int nt = 0; nt < 8; ++nt) {
        float g = gf[nt * 16 + l16], bb = bgf[nt * 16 + l16];
        #pragma unroll
        for (int mt = 0; mt < 2; ++mt)
        #pragma unroll
        for (int r = 0; r < 4; ++r) {
            float x = (accA[mt][nt][r] - meanS[mt][r]) * rstdS[mt][r] * g + bb;
            b2[(mt * 16 + quad * 4 + r) * 136 + nt * 16 + l16] = f2bf(gelu_fast(x));
        }
    }

    // ---- attention: per-head q/k GEMMs + DPP-reduced scores + softmax ----
    bf16x8 afE[2][4], afF[2][4];
    load_af<4>(afE, b1, 136, lane);   // ep
    load_af<4>(afF, b2, 136, lane);   // fp

    float a0v[4][2][4];               // attn weight (token 0) per [head][mtile][reg]
    {
        float bq8[8], bk8[8];
        #pragma unroll
        for (int nt = 0; nt < 8; ++nt) { bq8[nt] = bq[nt * 16 + l16]; bk8[nt] = bk[nt * 16 + l16]; }
        #pragma unroll
        for (int h = 0; h < 4; ++h) {
            float accQ[2][2][4], accKE[2][2][4], accKF[2][2][4];
            gemm_wf<4, 2>(afE, ws + OFF_Wq, bq8, 2 * h, accQ, lane);
            gemm_wf<4, 2>(afE, ws + OFF_Wk, bk8, 2 * h, accKE, lane);
            gemm_wf<4, 2>(afF, ws + OFF_Wk, bk8, 2 * h, accKF, lane);
            #pragma unroll
            for (int mt = 0; mt < 2; ++mt)
            #pragma unroll
            for (int r = 0; r < 4; ++r) {
                float p0 = accQ[mt][0][r] * accKE[mt][0][r] + accQ[mt][1][r] * accKE[mt][1][r];
                float p1 = accQ[mt][0][r] * accKF[mt][0][r] + accQ[mt][1][r] * accKF[mt][1][r];
                p0 = rowsum16(p0); p1 = rowsum16(p1);
                float s0 = p0 * SCALE, s1 = p1 * SCALE;
                float mx = fmaxf(s0, s1);
                float e0 = __expf(s0 - mx), e1 = __expf(s1 - mx);
                a0v[h][mt][r] = e0 * __builtin_amdgcn_rcpf(e0 + e1);
            }
        }
    }

    // ---- ctx = a0*v_e + (1-a0)*v_f  (v GEMMs folded per-ntile) ----
    {
        float bv8[8];
        #pragma unroll
        for (int nt = 0; nt < 8; ++nt) bv8[nt] = bv[nt * 16 + l16];
        #pragma unroll
        for (int nt = 0; nt < 8; ++nt) {
            float b = bv8[nt];
            f32x4 v0 = {b, b, b, b}, v1 = {b, b, b, b};
            const ushort_t* bp = ws + OFF_Wv + (size_t)nt * 4 * 512 + lane * 8;
            #pragma unroll
            for (int ks = 0; ks < 4; ++ks) {
                bf16x8 bb = *(const bf16x8*)(bp + ks * 512);
                v0 = __builtin_amdgcn_mfma_f32_16x16x32_bf16(afE[0][ks], bb, v0, 0, 0, 0);
                v1 = __builtin_amdgcn_mfma_f32_16x16x32_bf16(afE[1][ks], bb, v1, 0, 0, 0);
            }
            int h = nt >> 1;
            #pragma unroll
            for (int r = 0; r < 4; ++r) {
                accA[0][nt][r] = a0v[h][0][r] * v0[r];
                accA[1][nt][r] = a0v[h][1][r] * v1[r];
            }
        }
        #pragma unroll
        for (int nt = 0; nt < 8; ++nt) {
            float b = bv8[nt];
            f32x4 v0 = {b, b, b, b}, v1 = {b, b, b, b};
            const ushort_t* bp = ws + OFF_Wv + (size_t)nt * 4 * 512 + lane * 8;
            #pragma unroll
            for (int ks = 0; ks < 4; ++ks) {
                bf16x8 bb = *(const bf16x8*)(bp + ks * 512);
                v0 = __builtin_amdgcn_mfma_f32_16x16x32_bf16(afF[0][ks], bb, v0, 0, 0, 0);
                v1 = __builtin_amdgcn_mfma_f32_16x16x32_bf16(afF[1][ks], bb, v1, 0, 0, 0);
            }
            int h = nt >> 1;
            #pragma unroll
            for (int r = 0; r < 4; ++r) {
                accA[0][nt][r] += (1.0f - a0v[h][0][r]) * v0[r];
                accA[1][nt][r] += (1.0f - a0v[h][1][r]) * v1[r];
            }
        }
    }
    // write ctx bf16 -> b1 (scatter; after all reads of ep from b1)
    #pragma unroll
    for (int nt = 0; nt < 8; ++nt)
        #pragma unroll
        for (int mt = 0; mt < 2; ++mt)
        #pragma unroll
        for (int r = 0; r < 4; ++r)
            b1[(mt * 16 + quad * 4 + r) * 136 + nt * 16 + l16] = f2bf(accA[mt][nt][r]);

    // ---- eeg_enh = ctx @ Wo + bo ; fusion with fp ; fused -> b1 (bf16) ----
    {
        bf16x8 afC[2][4];
        load_af<4>(afC, b1, 136, lane);
        #pragma unroll
        for (int nt = 0; nt < 8; ++nt) bias8[nt] = bo[nt * 16 + l16];
        gemm_wf<4, 8>(afC, ws + OFF_Wo, bias8, 0, accA, lane);
    }
    {
        float t = temperature[0];
        float l0 = fusion_logits[0] / t, l1 = fusion_logits[1] / t;
        float mx = fmaxf(l0, l1);
        float e0 = __expf(l0 - mx), e1 = __expf(l1 - mx);
        float w0 = e0 / (e0 + e1), w1 = 1.0f - w0;
        #pragma unroll
        for (int nt = 0; nt < 8; ++nt)
            #pragma unroll
            for (int mt = 0; mt < 2; ++mt)
            #pragma unroll
            for (int r = 0; r < 4; ++r) {
                int off = (mt * 16 + quad * 4 + r) * 136 + nt * 16 + l16;
                float fp = bf2f(b2[off]);
                b1[off] = f2bf(w0 * accA[mt][nt][r] + w1 * fp);
            }
    }

    // ---- classifier: fused @ Wc1 + bc1 ; LN ; ReLU ; logits ----
    float accH[2][4][4];
    {
        bf16x8 afU[2][4];
        load_af<4>(afU, b1, 136, lane);
        float bc18[4];
        #pragma unroll
        for (int nt = 0; nt < 4; ++nt) bc18[nt] = bc1[nt * 16 + l16];
        gemm_wf<4, 4>(afU, ws + OFF_Wc1, bc18, 0, accH, lane);
    }
    #pragma unroll
    for (int mt = 0; mt < 2; ++mt)
    #pragma unroll
    for (int r = 0; r < 4; ++r) {
        float s = 0.f, ss = 0.f;
        #pragma unroll
        for (int nt = 0; nt < 4; ++nt) { float x = accH[mt][nt][r]; s += x; ss = fmaf(x, x, ss); }
        s = rowsum16(s); ss = rowsum16(ss);
        float m = s * (1.f / 64.f);
        meanS[mt][r] = m;
        rstdS[mt][r] = rsqrtf(ss * (1.f / 64.f) - m * m + EPS);
    }
    #pragma unroll
    for (int nt = 0; nt < 4; ++nt) {
        float g = gc[nt * 16 + l16], bb = bgc[nt * 16 + l16];
        #pragma unroll
        for (int mt = 0; mt < 2; ++mt)
        #pragma unroll
        for (int r = 0; r < 4; ++r) {
            float x = (accH[mt][nt][r] - meanS[mt][r]) * rstdS[mt][r] * g + bb;
            accH[mt][nt][r] = fmaxf(x, 0.0f);
        }
    }
    {
        float w2v[4][2];
        #pragma unroll
        for (int nt = 0; nt < 4; ++nt) {
            float2 w = *(const float2*)&Wc2[(nt * 16 + l16) * 2];
            w2v[nt][0] = w.x; w2v[nt][1] = w.y;
        }
        float o0c = bc2[0], o1c = bc2[1];
        #pragma unroll
        for (int mt = 0; mt < 2; ++mt)
        #pragma unroll
        for (int r = 0; r < 4; ++r) {
            float p0 = 0.f, p1 = 0.f;
            #pragma unroll
            for (int nt = 0; nt < 4; ++nt) {
                float hv = accH[mt][nt][r];
                p0 = fmaf(hv, w2v[nt][0], p0);
                p1 = fmaf(hv, w2v[nt][1], p1);
            }
            p0 = rowsum16(p0); p1 = rowsum16(p1);
            if (l16 == 0) {
                int row = rowbase + mt * 16 + quad * 4 + r;
                float2 o; o.x = p0 + o0c; o.y = p1 + o1c;
                *(float2*)&out[row * 2] = o;
            }
        }
    }
}

extern "C" void kernel_launch(void* const* d_in, const int* in_sizes, int n_in,
                              void* d_out, int out_size, void* d_ws, size_t ws_size,
                              hipStream_t stream) {
    const float* eeg  = (const float*)d_in[0];
    const float* fmri = (const float*)d_in[1];
    const float* We   = (const float*)d_in[2];
    const float* be   = (const float*)d_in[3];
    const float* ge   = (const float*)d_in[4];
    const float* bge  = (const float*)d_in[5];
    const float* Wf   = (const float*)d_in[6];
    const float* bf   = (const float*)d_in[7];
    const float* gf   = (const float*)d_in[8];
    const float* bgf  = (const float*)d_in[9];
    const float* Wq   = (const float*)d_in[10];
    const float* bq   = (const float*)d_in[11];
    const float* Wk   = (const float*)d_in[12];
    const float* bk   = (const float*)d_in[13];
    const float* Wv   = (const float*)d_in[14];
    const float* bv   = (const float*)d_in[15];
    const float* Wo   = (const float*)d_in[16];
    const float* bo   = (const float*)d_in[17];
    const float* fl   = (const float*)d_in[18];
    const float* temp = (const float*)d_in[19];
    const float* Wc1  = (const float*)d_in[20];
    const float* bc1  = (const float*)d_in[21];
    const float* gc   = (const float*)d_in[22];
    const float* bgc  = (const float*)d_in[23];
    const float* Wc2  = (const float*)d_in[24];
    const float* bc2  = (const float*)d_in[25];
    float* out = (float*)d_out;
    ushort_t* ws = (ushort_t*)d_ws;

    hipLaunchKernelGGL(pack_all, dim3((PACK_TOTAL + 255) / 256), dim3(256), 0, stream,
                       We, Wf, Wq, Wk, Wv, Wo, Wc1, ws);

    int B = in_sizes[0] / 128;     // 131072
    int grid = B / 64;             // 2048 blocks x 128 threads (2 waves x 32 rows)
    hipLaunchKernelGGL(fusion_wave, dim3(grid), dim3(128), 0, stream,
                       eeg, fmri, be, ge, bge, bf, gf, bgf,
                       bq, bk, bv, bo, fl, temp, bc1, gc, bgc, Wc2, bc2,
                       ws, out);
}

// Round 5
// 329.801 us; speedup vs baseline: 1.1212x; 1.1212x over previous
//
#include <hip/hip_runtime.h>
#include <math.h>

#define EPS 1e-5f
#define SCALE 0.17677669529663687f   // 1/sqrt(32)

// packed bf16 weight offsets in d_ws (ushort units)
#define OFF_We  0
#define OFF_Wf  16384
#define OFF_Wq  24576
#define OFF_Wk  40960
#define OFF_Wv  57344
#define OFF_Wo  73728
#define OFF_Wc1 90112
#define PACK_TOTAL 98304

typedef __bf16 bf16x8 __attribute__((ext_vector_type(8)));
typedef float f32x4 __attribute__((ext_vector_type(4)));
typedef unsigned short ushort_t;
typedef unsigned short ushortx4 __attribute__((ext_vector_type(4)));

__device__ __forceinline__ ushort_t f2bf(float x) {
    unsigned u = __builtin_bit_cast(unsigned, x);
    u = (u + 0x7fffu + ((u >> 16) & 1u)) >> 16;   // RNE
    return (ushort_t)u;
}
__device__ __forceinline__ float bf2f(ushort_t v) {
    unsigned u = ((unsigned)v) << 16;
    return __builtin_bit_cast(float, u);
}

// 16-lane (DPP-row) all-lanes sum via row_ror butterfly — VALU pipe, no LDS.
#define DPPADD(x, ctrl) \
    ((x) + __builtin_bit_cast(float, __builtin_amdgcn_update_dpp( \
        __builtin_bit_cast(int, (x)), __builtin_bit_cast(int, (x)), (ctrl), 0xF, 0xF, false)))

__device__ __forceinline__ float rowsum16(float x) {
    x = DPPADD(x, 0x121);   // row_ror:1
    x = DPPADD(x, 0x122);   // row_ror:2
    x = DPPADD(x, 0x124);   // row_ror:4
    x = DPPADD(x, 0x128);   // row_ror:8
    return x;
}

// tanh-form GELU via sigmoid + HW exp; |err| <= ~4e-4 vs exact erf GELU
__device__ __forceinline__ float gelu_fast(float x) {
    float x2 = x * x;
    float u = x * fmaf(0.07135481283f, x2, 1.5957691216f);
    float e = __expf(-u);
    return x * __builtin_amdgcn_rcpf(1.0f + e);
}

// ---------------- weight pack kernel (verified r2/r3 — restored verbatim) ----------------
__global__ __launch_bounds__(256) void pack_all(
    const float* __restrict__ We, const float* __restrict__ Wf,
    const float* __restrict__ Wq, const float* __restrict__ Wk,
    const float* __restrict__ Wv, const float* __restrict__ Wo,
    const float* __restrict__ Wc1, ushort_t* __restrict__ ws)
{
    int o = blockIdx.x * 256 + threadIdx.x;
    if (o >= PACK_TOTAL) return;
    const float* W; int K, N, base;
    if (o < OFF_Wf)        { W = We;  K = 128; N = 128; base = OFF_We; }
    else if (o < OFF_Wq)   { W = Wf;  K = 64;  N = 128; base = OFF_Wf; }
    else if (o < OFF_Wk)   { W = Wq;  K = 128; N = 128; base = OFF_Wq; }
    else if (o < OFF_Wv)   { W = Wk;  K = 128; N = 128; base = OFF_Wk; }
    else if (o < OFF_Wo)   { W = Wv;  K = 128; N = 128; base = OFF_Wv; }
    else if (o < OFF_Wc1)  { W = Wo;  K = 128; N = 128; base = OFF_Wo; }
    else                   { W = Wc1; K = 128; N = 64;  base = OFF_Wc1; }
    int e = o - base;
    int j = e & 7, l = (e >> 3) & 63, rest = e >> 9;
    int KS = K >> 5;
    int s = rest % KS, t = rest / KS;
    int k = s * 32 + ((l >> 4) << 3) + j;
    int n = (t << 4) + (l & 15);
    ws[o] = f2bf(W[k * N + n]);
}

// ---------------- GEMM helpers ----------------
// preheld-A variant (A-fragments already in registers)
template<int KS>
__device__ __forceinline__ void load_af(bf16x8 af[2][KS], const ushort_t* A,
                                        int strideA, int lane)
{
    const int quad = lane >> 4, l16 = lane & 15;
    #pragma unroll
    for (int mt = 0; mt < 2; ++mt)
        #pragma unroll
        for (int ks = 0; ks < KS; ++ks)
            af[mt][ks] = *(const bf16x8*)(A + (mt * 16 + l16) * strideA + ks * 32 + quad * 8);
}

template<int KS, int NTN>
__device__ __forceinline__ void mma_pre(const bf16x8 af[2][KS],
    const ushort_t* __restrict__ Wp, const float* __restrict__ biasg,
    int nt0, float acc[2][NTN][4], int lane)
{
    const int l16 = lane & 15;
    #pragma unroll
    for (int t = 0; t < NTN; ++t) {
        float b = biasg[(nt0 + t) * 16 + l16];
        f32x4 a0 = {b, b, b, b}, a1 = {b, b, b, b};
        const ushort_t* bp = Wp + (size_t)(nt0 + t) * KS * 512 + lane * 8;
        #pragma unroll
        for (int ks = 0; ks < KS; ++ks) {
            bf16x8 bb = *(const bf16x8*)(bp + ks * 512);
            a0 = __builtin_amdgcn_mfma_f32_16x16x32_bf16(af[0][ks], bb, a0, 0, 0, 0);
            a1 = __builtin_amdgcn_mfma_f32_16x16x32_bf16(af[1][ks], bb, a1, 0, 0, 0);
        }
        #pragma unroll
        for (int r = 0; r < 4; ++r) { acc[0][t][r] = a0[r]; acc[1][t][r] = a1[r]; }
    }
}

// ks-chunked variant: A-frags loaded 8 regs at a time inside the k-loop.
// asm anti-CSE keeps LLVM from hoisting the loads into a persistent array.
template<int KS, int NTN>
__device__ __forceinline__ void gemm_ks(const ushort_t* A, int strideA,
    const ushort_t* __restrict__ Wp, const float* __restrict__ biasg,
    int nt0, float acc[2][NTN][4], int lane)
{
    const int quad = lane >> 4, l16 = lane & 15;
    int off0 = l16 * strideA + quad * 8;
    asm volatile("" : "+v"(off0));
    f32x4 a[2][NTN];
    #pragma unroll
    for (int t = 0; t < NTN; ++t) {
        float b = biasg[(nt0 + t) * 16 + l16];
        a[0][t] = (f32x4){b, b, b, b};
        a[1][t] = (f32x4){b, b, b, b};
    }
    #pragma unroll
    for (int ks = 0; ks < KS; ++ks) {
        bf16x8 af0 = *(const bf16x8*)(A + off0 + ks * 32);
        bf16x8 af1 = *(const bf16x8*)(A + off0 + 16 * strideA + ks * 32);
        #pragma unroll
        for (int t = 0; t < NTN; ++t) {
            bf16x8 bb = *(const bf16x8*)(Wp + ((size_t)(nt0 + t) * KS + ks) * 512 + lane * 8);
            a[0][t] = __builtin_amdgcn_mfma_f32_16x16x32_bf16(af0, bb, a[0][t], 0, 0, 0);
            a[1][t] = __builtin_amdgcn_mfma_f32_16x16x32_bf16(af1, bb, a[1][t], 0, 0, 0);
        }
    }
    #pragma unroll
    for (int t = 0; t < NTN; ++t)
        #pragma unroll
        for (int r = 0; r < 4; ++r) { acc[0][t][r] = a[0][t][r]; acc[1][t][r] = a[1][t][r]; }
}

// ---------------- main kernel: barrier-free, wave-private 32 rows ----------------
__global__ __launch_bounds__(128, 2) void fusion_wave(
    const float* __restrict__ eeg, const float* __restrict__ fmri,
    const float* __restrict__ be, const float* __restrict__ ge, const float* __restrict__ bge,
    const float* __restrict__ bfb, const float* __restrict__ gf, const float* __restrict__ bgf,
    const float* __restrict__ bq, const float* __restrict__ bk, const float* __restrict__ bv,
    const float* __restrict__ bo,
    const float* __restrict__ fusion_logits, const float* __restrict__ temperature,
    const float* __restrict__ bc1, const float* __restrict__ gc, const float* __restrict__ bgc,
    const float* __restrict__ Wc2, const float* __restrict__ bc2,
    const ushort_t* __restrict__ ws, float* __restrict__ out)
{
    __shared__ __align__(16) ushort_t B1[2][32 * 136];   // eeg raw -> ep -> ctx -> fused
    __shared__ __align__(16) ushort_t B2[2][32 * 136];   // fmri raw -> fp

    const int tid = threadIdx.x;
    const int wave = tid >> 6, lane = tid & 63;
    const int quad = lane >> 4, l16 = lane & 15;
    const int rowbase = blockIdx.x * 64 + wave * 32;
    ushort_t* b1 = B1[wave];
    ushort_t* b2 = B2[wave];

    // ---- stage raw inputs -> bf16 A-layout LDS (wave-private, no barrier) ----
    {
        const float4* src = (const float4*)(eeg + (size_t)rowbase * 128);
        #pragma unroll
        for (int i = 0; i < 16; ++i) {
            int idx = i * 64 + lane;
            float4 v = src[idx];
            int r = idx >> 5, k4 = (idx & 31) * 4;
            *(ushortx4*)&b1[r * 136 + k4] =
                (ushortx4){f2bf(v.x), f2bf(v.y), f2bf(v.z), f2bf(v.w)};
        }
        const float4* srcf = (const float4*)(fmri + (size_t)rowbase * 64);
        #pragma unroll
        for (int i = 0; i < 8; ++i) {
            int idx = i * 64 + lane;
            float4 v = srcf[idx];
            int r = idx >> 4, k4 = (idx & 15) * 4;
            *(ushortx4*)&b2[r * 136 + k4] =
                (ushortx4){f2bf(v.x), f2bf(v.y), f2bf(v.z), f2bf(v.w)};
        }
    }

    float meanS[2][4], rstdS[2][4];

    // ---- eeg @ We + be ; LN ; GELU -> ep (bf16, in-place into b1) ----
    {
        float acc[2][8][4];
        gemm_ks<4, 8>(b1, 136, ws + OFF_We, be, 0, acc, lane);
        #pragma unroll
        for (int mt = 0; mt < 2; ++mt)
        #pragma unroll
        for (int r = 0; r < 4; ++r) {
            float s = 0.f, ss = 0.f;
            #pragma unroll
            for (int nt = 0; nt < 8; ++nt) { float x = acc[mt][nt][r]; s += x; ss = fmaf(x, x, ss); }
            s = rowsum16(s); ss = rowsum16(ss);
            float m = s * (1.f / 128.f);
            meanS[mt][r] = m;
            rstdS[mt][r] = rsqrtf(ss * (1.f / 128.f) - m * m + EPS);
        }
        #pragma unroll
        for (int nt = 0; nt < 8; ++nt) {
            float g = ge[nt * 16 + l16], bb = bge[nt * 16 + l16];
            #pragma unroll
            for (int mt = 0; mt < 2; ++mt)
            #pragma unroll
            for (int r = 0; r < 4; ++r) {
                float x = (acc[mt][nt][r] - meanS[mt][r]) * rstdS[mt][r] * g + bb;
                b1[(mt * 16 + quad * 4 + r) * 136 + nt * 16 + l16] = f2bf(gelu_fast(x));
            }
        }
    }

    // ---- fmri @ Wf + bf ; LN ; GELU -> fp (bf16, in-place into b2) ----
    {
        float acc[2][8][4];
        gemm_ks<2, 8>(b2, 136, ws + OFF_Wf, bfb, 0, acc, lane);
        #pragma unroll
        for (int mt = 0; mt < 2; ++mt)
        #pragma unroll
        for (int r = 0; r < 4; ++r) {
            float s = 0.f, ss = 0.f;
            #pragma unroll
            for (int nt = 0; nt < 8; ++nt) { float x = acc[mt][nt][r]; s += x; ss = fmaf(x, x, ss); }
            s = rowsum16(s); ss = rowsum16(ss);
            float m = s * (1.f / 128.f);
            meanS[mt][r] = m;
            rstdS[mt][r] = rsqrtf(ss * (1.f / 128.f) - m * m + EPS);
        }
        #pragma unroll
        for (int nt = 0; nt < 8; ++nt) {
            float g = gf[nt * 16 + l16], bb = bgf[nt * 16 + l16];
            #pragma unroll
            for (int mt = 0; mt < 2; ++mt)
            #pragma unroll
            for (int r = 0; r < 4; ++r) {
                float x = (acc[mt][nt][r] - meanS[mt][r]) * rstdS[mt][r] * g + bb;
                b2[(mt * 16 + quad * 4 + r) * 136 + nt * 16 + l16] = f2bf(gelu_fast(x));
            }
        }
    }

    // ---- attention ----
    // afE held in regs (32 VGPRs): reused for Q, K_e, V_e AND frees b1 for ctx writes.
    bf16x8 afE[2][4];
    load_af<4>(afE, b1, 136, lane);

    float a0v[4][2][4];               // attn weight (token 0) per [head][mtile][reg]
    #pragma unroll
    for (int h = 0; h < 4; ++h) {
        float accQ[2][2][4], accKE[2][2][4], accKF[2][2][4];
        mma_pre<4, 2>(afE, ws + OFF_Wq, bq, 2 * h, accQ, lane);
        mma_pre<4, 2>(afE, ws + OFF_Wk, bk, 2 * h, accKE, lane);
        gemm_ks<4, 2>(b2, 136, ws + OFF_Wk, bk, 2 * h, accKF, lane);
        #pragma unroll
        for (int mt = 0; mt < 2; ++mt)
        #pragma unroll
        for (int r = 0; r < 4; ++r) {
            float p0 = accQ[mt][0][r] * accKE[mt][0][r] + accQ[mt][1][r] * accKE[mt][1][r];
            float p1 = accQ[mt][0][r] * accKF[mt][0][r] + accQ[mt][1][r] * accKF[mt][1][r];
            p0 = rowsum16(p0); p1 = rowsum16(p1);
            float s0 = p0 * SCALE, s1 = p1 * SCALE;
            float mx = fmaxf(s0, s1);
            float e0 = __expf(s0 - mx), e1 = __expf(s1 - mx);
            a0v[h][mt][r] = e0 * __builtin_amdgcn_rcpf(e0 + e1);
        }
    }

    // ---- ctx per n-tile: ve (afE regs) + vf (JIT from b2), combine, write -> b1 ----
    #pragma unroll
    for (int nt = 0; nt < 8; ++nt) {
        float bvv = bv[nt * 16 + l16];
        f32x4 e0 = {bvv, bvv, bvv, bvv}, e1 = {bvv, bvv, bvv, bvv};
        f32x4 f0 = {bvv, bvv, bvv, bvv}, f1 = {bvv, bvv, bvv, bvv};
        int off0 = l16 * 136 + quad * 8;
        asm volatile("" : "+v"(off0));
        const ushort_t* bp = ws + OFF_Wv + (size_t)nt * 4 * 512 + lane * 8;
        #pragma unroll
        for (int ks = 0; ks < 4; ++ks) {
            bf16x8 bb = *(const bf16x8*)(bp + ks * 512);
            e0 = __builtin_amdgcn_mfma_f32_16x16x32_bf16(afE[0][ks], bb, e0, 0, 0, 0);
            e1 = __builtin_amdgcn_mfma_f32_16x16x32_bf16(afE[1][ks], bb, e1, 0, 0, 0);
            bf16x8 af0 = *(const bf16x8*)(b2 + off0 + ks * 32);
            bf16x8 af1 = *(const bf16x8*)(b2 + off0 + 16 * 136 + ks * 32);
            f0 = __builtin_amdgcn_mfma_f32_16x16x32_bf16(af0, bb, f0, 0, 0, 0);
            f1 = __builtin_amdgcn_mfma_f32_16x16x32_bf16(af1, bb, f1, 0, 0, 0);
        }
        int h = nt >> 1;
        #pragma unroll
        for (int r = 0; r < 4; ++r) {
            float a0 = a0v[h][0][r];
            float c0 = a0 * e0[r] + (1.0f - a0) * f0[r];
            float a1 = a0v[h][1][r];
            float c1 = a1 * e1[r] + (1.0f - a1) * f1[r];
            b1[(quad * 4 + r) * 136 + nt * 16 + l16] = f2bf(c0);
            b1[(16 + quad * 4 + r) * 136 + nt * 16 + l16] = f2bf(c1);
        }
    }

    // ---- eeg_enh = ctx @ Wo + bo ; fusion with fp ; fused -> b1 (bf16) ----
    {
        float acc[2][8][4];
        gemm_ks<4, 8>(b1, 136, ws + OFF_Wo, bo, 0, acc, lane);
        float t = temperature[0];
        float l0 = fusion_logits[0] / t, l1 = fusion_logits[1] / t;
        float mx = fmaxf(l0, l1);
        float ee0 = __expf(l0 - mx), ee1 = __expf(l1 - mx);
        float w0 = ee0 / (ee0 + ee1), w1 = 1.0f - w0;
        #pragma unroll
        for (int nt = 0; nt < 8; ++nt)
            #pragma unroll
            for (int mt = 0; mt < 2; ++mt)
            #pragma unroll
            for (int r = 0; r < 4; ++r) {
                int off = (mt * 16 + quad * 4 + r) * 136 + nt * 16 + l16;
                float fp = bf2f(b2[off]);
                b1[off] = f2bf(w0 * acc[mt][nt][r] + w1 * fp);
            }
    }

    // ---- classifier: fused @ Wc1 + bc1 ; LN ; ReLU ; logits ----
    float accH[2][4][4];
    gemm_ks<4, 4>(b1, 136, ws + OFF_Wc1, bc1, 0, accH, lane);
    #pragma unroll
    for (int mt = 0; mt < 2; ++mt)
    #pragma unroll
    for (int r = 0; r < 4; ++r) {
        float s = 0.f, ss = 0.f;
        #pragma unroll
        for (int nt = 0; nt < 4; ++nt) { float x = accH[mt][nt][r]; s += x; ss = fmaf(x, x, ss); }
        s = rowsum16(s); ss = rowsum16(ss);
        float m = s * (1.f / 64.f);
        meanS[mt][r] = m;
        rstdS[mt][r] = rsqrtf(ss * (1.f / 64.f) - m * m + EPS);
    }
    #pragma unroll
    for (int nt = 0; nt < 4; ++nt) {
        float g = gc[nt * 16 + l16], bb = bgc[nt * 16 + l16];
        #pragma unroll
        for (int mt = 0; mt < 2; ++mt)
        #pragma unroll
        for (int r = 0; r < 4; ++r) {
            float x = (accH[mt][nt][r] - meanS[mt][r]) * rstdS[mt][r] * g + bb;
            accH[mt][nt][r] = fmaxf(x, 0.0f);
        }
    }
    {
        float w2v[4][2];
        #pragma unroll
        for (int nt = 0; nt < 4; ++nt) {
            float2 w = *(const float2*)&Wc2[(nt * 16 + l16) * 2];
            w2v[nt][0] = w.x; w2v[nt][1] = w.y;
        }
        float o0c = bc2[0], o1c = bc2[1];
        #pragma unroll
        for (int mt = 0; mt < 2; ++mt)
        #pragma unroll
        for (int r = 0; r < 4; ++r) {
            float p0 = 0.f, p1 = 0.f;
            #pragma unroll
            for (int nt = 0; nt < 4; ++nt) {
                float hv = accH[mt][nt][r];
                p0 = fmaf(hv, w2v[nt][0], p0);
                p1 = fmaf(hv, w2v[nt][1], p1);
            }
            p0 = rowsum16(p0); p1 = rowsum16(p1);
            if (l16 == 0) {
                int row = rowbase + mt * 16 + quad * 4 + r;
                float2 o; o.x = p0 + o0c; o.y = p1 + o1c;
                *(float2*)&out[row * 2] = o;
            }
        }
    }
}

extern "C" void kernel_launch(void* const* d_in, const int* in_sizes, int n_in,
                              void* d_out, int out_size, void* d_ws, size_t ws_size,
                              hipStream_t stream) {
    const float* eeg  = (const float*)d_in[0];
    const float* fmri = (const float*)d_in[1];
    const float* We   = (const float*)d_in[2];
    const float* be   = (const float*)d_in[3];
    const float* ge   = (const float*)d_in[4];
    const float* bge  = (const float*)d_in[5];
    const float* Wf   = (const float*)d_in[6];
    const float* bf   = (const float*)d_in[7];
    const float* gf   = (const float*)d_in[8];
    const float* bgf  = (const float*)d_in[9];
    const float* Wq   = (const float*)d_in[10];
    const float* bq   = (const float*)d_in[11];
    const float* Wk   = (const float*)d_in[12];
    const float* bk   = (const float*)d_in[13];
    const float* Wv   = (const float*)d_in[14];
    const float* bv   = (const float*)d_in[15];
    const float* Wo   = (const float*)d_in[16];
    const float* bo   = (const float*)d_in[17];
    const float* fl   = (const float*)d_in[18];
    const float* temp = (const float*)d_in[19];
    const float* Wc1  = (const float*)d_in[20];
    const float* bc1  = (const float*)d_in[21];
    const float* gc   = (const float*)d_in[22];
    const float* bgc  = (const float*)d_in[23];
    const float* Wc2  = (const float*)d_in[24];
    const float* bc2  = (const float*)d_in[25];
    float* out = (float*)d_out;
    ushort_t* ws = (ushort_t*)d_ws;

    hipLaunchKernelGGL(pack_all, dim3((PACK_TOTAL + 255) / 256), dim3(256), 0, stream,
                       We, Wf, Wq, Wk, Wv, Wo, Wc1, ws);

    int B = in_sizes[0] / 128;     // 131072
    int grid = B / 64;             // 2048 blocks x 128 threads (2 waves x 32 rows)
    hipLaunchKernelGGL(fusion_wave, dim3(grid), dim3(128), 0, stream,
                       eeg, fmri, be, ge, bge, bf, gf, bgf,
                       bq, bk, bv, bo, fl, temp, bc1, gc, bgc, Wc2, bc2,
                       ws, out);
}

// Round 6
// 294.113 us; speedup vs baseline: 1.2572x; 1.1213x over previous
//
#include <hip/hip_runtime.h>
#include <math.h>

#define EPS 1e-5f
#define SCALE 0.17677669529663687f   // 1/sqrt(32)

// packed bf16 weight offsets in d_ws (ushort units)
#define OFF_We  0
#define OFF_Wf  16384
#define OFF_Wq  24576
#define OFF_Wk  40960
#define OFF_Wv  57344
#define OFF_Wo  73728
#define OFF_Wc1 90112
#define PACK_TOTAL 98304

typedef __bf16 bf16x8 __attribute__((ext_vector_type(8)));
typedef float f32x4 __attribute__((ext_vector_type(4)));
typedef unsigned short ushort_t;
typedef unsigned short ushortx4 __attribute__((ext_vector_type(4)));

__device__ __forceinline__ ushort_t f2bf(float x) {
    unsigned u = __builtin_bit_cast(unsigned, x);
    u = (u + 0x7fffu + ((u >> 16) & 1u)) >> 16;   // RNE
    return (ushort_t)u;
}
__device__ __forceinline__ float bf2f(ushort_t v) {
    unsigned u = ((unsigned)v) << 16;
    return __builtin_bit_cast(float, u);
}

// 16-lane (DPP-row) all-lanes sum via row_ror butterfly — VALU pipe, no LDS.
#define DPPADD(x, ctrl) \
    ((x) + __builtin_bit_cast(float, __builtin_amdgcn_update_dpp( \
        __builtin_bit_cast(int, (x)), __builtin_bit_cast(int, (x)), (ctrl), 0xF, 0xF, false)))

__device__ __forceinline__ float rowsum16(float x) {
    x = DPPADD(x, 0x121);   // row_ror:1
    x = DPPADD(x, 0x122);   // row_ror:2
    x = DPPADD(x, 0x124);   // row_ror:4
    x = DPPADD(x, 0x128);   // row_ror:8
    return x;
}

// tanh-form GELU via sigmoid + HW exp; |err| <= ~4e-4 vs exact erf GELU
__device__ __forceinline__ float gelu_fast(float x) {
    float x2 = x * x;
    float u = x * fmaf(0.07135481283f, x2, 1.5957691216f);
    float e = __expf(-u);
    return x * __builtin_amdgcn_rcpf(1.0f + e);
}

// ---------------- weight pack kernel (verified r2/r3/r5) ----------------
__global__ __launch_bounds__(256) void pack_all(
    const float* __restrict__ We, const float* __restrict__ Wf,
    const float* __restrict__ Wq, const float* __restrict__ Wk,
    const float* __restrict__ Wv, const float* __restrict__ Wo,
    const float* __restrict__ Wc1, ushort_t* __restrict__ ws)
{
    int o = blockIdx.x * 256 + threadIdx.x;
    if (o >= PACK_TOTAL) return;
    const float* W; int K, N, base;
    if (o < OFF_Wf)        { W = We;  K = 128; N = 128; base = OFF_We; }
    else if (o < OFF_Wq)   { W = Wf;  K = 64;  N = 128; base = OFF_Wf; }
    else if (o < OFF_Wk)   { W = Wq;  K = 128; N = 128; base = OFF_Wq; }
    else if (o < OFF_Wv)   { W = Wk;  K = 128; N = 128; base = OFF_Wk; }
    else if (o < OFF_Wo)   { W = Wv;  K = 128; N = 128; base = OFF_Wv; }
    else if (o < OFF_Wc1)  { W = Wo;  K = 128; N = 128; base = OFF_Wo; }
    else                   { W = Wc1; K = 128; N = 64;  base = OFF_Wc1; }
    int e = o - base;
    int j = e & 7, l = (e >> 3) & 63, rest = e >> 9;
    int KS = K >> 5;
    int s = rest % KS, t = rest / KS;
    int k = s * 32 + ((l >> 4) << 3) + j;
    int n = (t << 4) + (l & 15);
    ws[o] = f2bf(W[k * N + n]);
}

// ---------------- GEMM helpers (16 rows per wave: single m-tile) ----------------
template<int KS>
__device__ __forceinline__ void load_af(bf16x8 af[KS], const ushort_t* A,
                                        int strideA, int lane)
{
    const int quad = lane >> 4, l16 = lane & 15;
    #pragma unroll
    for (int ks = 0; ks < KS; ++ks)
        af[ks] = *(const bf16x8*)(A + l16 * strideA + ks * 32 + quad * 8);
}

template<int KS, int NTN>
__device__ __forceinline__ void mma_pre(const bf16x8 af[KS],
    const ushort_t* __restrict__ Wp, const float* __restrict__ biasg,
    int nt0, float acc[NTN][4], int lane)
{
    const int l16 = lane & 15;
    #pragma unroll
    for (int t = 0; t < NTN; ++t) {
        float b = biasg[(nt0 + t) * 16 + l16];
        f32x4 a0 = {b, b, b, b};
        const ushort_t* bp = Wp + (size_t)(nt0 + t) * KS * 512 + lane * 8;
        #pragma unroll
        for (int ks = 0; ks < KS; ++ks) {
            bf16x8 bb = *(const bf16x8*)(bp + ks * 512);
            a0 = __builtin_amdgcn_mfma_f32_16x16x32_bf16(af[ks], bb, a0, 0, 0, 0);
        }
        #pragma unroll
        for (int r = 0; r < 4; ++r) acc[t][r] = a0[r];
    }
}

// ks-chunked variant: A-frags loaded JIT inside the k-loop (anti-CSE guard).
template<int KS, int NTN>
__device__ __forceinline__ void gemm_ks(const ushort_t* A, int strideA,
    const ushort_t* __restrict__ Wp, const float* __restrict__ biasg,
    int nt0, float acc[NTN][4], int lane)
{
    const int quad = lane >> 4, l16 = lane & 15;
    int off0 = l16 * strideA + quad * 8;
    asm volatile("" : "+v"(off0));
    f32x4 a[NTN];
    #pragma unroll
    for (int t = 0; t < NTN; ++t) {
        float b = biasg[(nt0 + t) * 16 + l16];
        a[t] = (f32x4){b, b, b, b};
    }
    #pragma unroll
    for (int ks = 0; ks < KS; ++ks) {
        bf16x8 af0 = *(const bf16x8*)(A + off0 + ks * 32);
        #pragma unroll
        for (int t = 0; t < NTN; ++t) {
            bf16x8 bb = *(const bf16x8*)(Wp + ((size_t)(nt0 + t) * KS + ks) * 512 + lane * 8);
            a[t] = __builtin_amdgcn_mfma_f32_16x16x32_bf16(af0, bb, a[t], 0, 0, 0);
        }
    }
    #pragma unroll
    for (int t = 0; t < NTN; ++t)
        #pragma unroll
        for (int r = 0; r < 4; ++r) acc[t][r] = a[t][r];
}

// ---------------- main kernel: barrier-free, wave-private 16 rows ----------------
__global__ __launch_bounds__(128, 4) void fusion_wave(
    const float* __restrict__ eeg, const float* __restrict__ fmri,
    const float* __restrict__ be, const float* __restrict__ ge, const float* __restrict__ bge,
    const float* __restrict__ bfb, const float* __restrict__ gf, const float* __restrict__ bgf,
    const float* __restrict__ bq, const float* __restrict__ bk, const float* __restrict__ bv,
    const float* __restrict__ bo,
    const float* __restrict__ fusion_logits, const float* __restrict__ temperature,
    const float* __restrict__ bc1, const float* __restrict__ gc, const float* __restrict__ bgc,
    const float* __restrict__ Wc2, const float* __restrict__ bc2,
    const ushort_t* __restrict__ ws, float* __restrict__ out)
{
    __shared__ __align__(16) ushort_t B1[2][16 * 136];   // eeg raw -> ep -> ctx -> fused
    __shared__ __align__(16) ushort_t B2[2][16 * 136];   // fmri raw -> fp

    const int tid = threadIdx.x;
    const int wave = tid >> 6, lane = tid & 63;
    const int quad = lane >> 4, l16 = lane & 15;
    const int rowbase = blockIdx.x * 32 + wave * 16;
    ushort_t* b1 = B1[wave];
    ushort_t* b2 = B2[wave];

    // ---- stage raw inputs -> bf16 A-layout LDS (wave-private, no barrier) ----
    {
        const float4* src = (const float4*)(eeg + (size_t)rowbase * 128);
        #pragma unroll
        for (int i = 0; i < 8; ++i) {
            int idx = i * 64 + lane;               // 512 float4 = 16 rows x 32
            float4 v = src[idx];
            int r = idx >> 5, k4 = (idx & 31) * 4;
            *(ushortx4*)&b1[r * 136 + k4] =
                (ushortx4){f2bf(v.x), f2bf(v.y), f2bf(v.z), f2bf(v.w)};
        }
        const float4* srcf = (const float4*)(fmri + (size_t)rowbase * 64);
        #pragma unroll
        for (int i = 0; i < 4; ++i) {
            int idx = i * 64 + lane;               // 256 float4 = 16 rows x 16
            float4 v = srcf[idx];
            int r = idx >> 4, k4 = (idx & 15) * 4;
            *(ushortx4*)&b2[r * 136 + k4] =
                (ushortx4){f2bf(v.x), f2bf(v.y), f2bf(v.z), f2bf(v.w)};
        }
    }

    float meanS[4], rstdS[4];

    // ---- eeg @ We + be ; LN ; GELU -> ep (bf16, in-place into b1) ----
    {
        float acc[8][4];
        gemm_ks<4, 8>(b1, 136, ws + OFF_We, be, 0, acc, lane);
        #pragma unroll
        for (int r = 0; r < 4; ++r) {
            float s = 0.f, ss = 0.f;
            #pragma unroll
            for (int nt = 0; nt < 8; ++nt) { float x = acc[nt][r]; s += x; ss = fmaf(x, x, ss); }
            s = rowsum16(s); ss = rowsum16(ss);
            float m = s * (1.f / 128.f);
            meanS[r] = m;
            rstdS[r] = rsqrtf(ss * (1.f / 128.f) - m * m + EPS);
        }
        #pragma unroll
        for (int nt = 0; nt < 8; ++nt) {
            float g = ge[nt * 16 + l16], bb = bge[nt * 16 + l16];
            #pragma unroll
            for (int r = 0; r < 4; ++r) {
                float x = (acc[nt][r] - meanS[r]) * rstdS[r] * g + bb;
                b1[(quad * 4 + r) * 136 + nt * 16 + l16] = f2bf(gelu_fast(x));
            }
        }
    }

    // ---- fmri @ Wf + bf ; LN ; GELU -> fp (bf16, in-place into b2) ----
    {
        float acc[8][4];
        gemm_ks<2, 8>(b2, 136, ws + OFF_Wf, bfb, 0, acc, lane);
        #pragma unroll
        for (int r = 0; r < 4; ++r) {
            float s = 0.f, ss = 0.f;
            #pragma unroll
            for (int nt = 0; nt < 8; ++nt) { float x = acc[nt][r]; s += x; ss = fmaf(x, x, ss); }
            s = rowsum16(s); ss = rowsum16(ss);
            float m = s * (1.f / 128.f);
            meanS[r] = m;
            rstdS[r] = rsqrtf(ss * (1.f / 128.f) - m * m + EPS);
        }
        #pragma unroll
        for (int nt = 0; nt < 8; ++nt) {
            float g = gf[nt * 16 + l16], bb = bgf[nt * 16 + l16];
            #pragma unroll
            for (int r = 0; r < 4; ++r) {
                float x = (acc[nt][r] - meanS[r]) * rstdS[r] * g + bb;
                b2[(quad * 4 + r) * 136 + nt * 16 + l16] = f2bf(gelu_fast(x));
            }
        }
    }

    // ---- attention ----
    // afE held in regs (16 VGPRs): reused for Q, K_e, V_e AND frees b1 for ctx writes.
    bf16x8 afE[4];
    load_af<4>(afE, b1, 136, lane);

    float a0v[4][4];                  // attn weight (token 0) per [head][reg]
    #pragma unroll
    for (int h = 0; h < 4; ++h) {
        float accQ[2][4], accKE[2][4], accKF[2][4];
        mma_pre<4, 2>(afE, ws + OFF_Wq, bq, 2 * h, accQ, lane);
        mma_pre<4, 2>(afE, ws + OFF_Wk, bk, 2 * h, accKE, lane);
        gemm_ks<4, 2>(b2, 136, ws + OFF_Wk, bk, 2 * h, accKF, lane);
        #pragma unroll
        for (int r = 0; r < 4; ++r) {
            float p0 = accQ[0][r] * accKE[0][r] + accQ[1][r] * accKE[1][r];
            float p1 = accQ[0][r] * accKF[0][r] + accQ[1][r] * accKF[1][r];
            p0 = rowsum16(p0); p1 = rowsum16(p1);
            float s0 = p0 * SCALE, s1 = p1 * SCALE;
            float mx = fmaxf(s0, s1);
            float e0 = __expf(s0 - mx), e1 = __expf(s1 - mx);
            a0v[h][r] = e0 * __builtin_amdgcn_rcpf(e0 + e1);
        }
    }

    // ---- ctx per n-tile: ve (afE regs) + vf (JIT from b2), combine, write -> b1 ----
    #pragma unroll
    for (int nt = 0; nt < 8; ++nt) {
        float bvv = bv[nt * 16 + l16];
        f32x4 e0 = {bvv, bvv, bvv, bvv};
        f32x4 f0 = {bvv, bvv, bvv, bvv};
        int off0 = l16 * 136 + quad * 8;
        asm volatile("" : "+v"(off0));
        const ushort_t* bp = ws + OFF_Wv + (size_t)nt * 4 * 512 + lane * 8;
        #pragma unroll
        for (int ks = 0; ks < 4; ++ks) {
            bf16x8 bb = *(const bf16x8*)(bp + ks * 512);
            e0 = __builtin_amdgcn_mfma_f32_16x16x32_bf16(afE[ks], bb, e0, 0, 0, 0);
            bf16x8 af0 = *(const bf16x8*)(b2 + off0 + ks * 32);
            f0 = __builtin_amdgcn_mfma_f32_16x16x32_bf16(af0, bb, f0, 0, 0, 0);
        }
        int h = nt >> 1;
        #pragma unroll
        for (int r = 0; r < 4; ++r) {
            float a0 = a0v[h][r];
            float c0 = a0 * e0[r] + (1.0f - a0) * f0[r];
            b1[(quad * 4 + r) * 136 + nt * 16 + l16] = f2bf(c0);
        }
    }

    // ---- eeg_enh = ctx @ Wo + bo ; fusion with fp ; fused -> b1 (bf16) ----
    {
        float acc[8][4];
        gemm_ks<4, 8>(b1, 136, ws + OFF_Wo, bo, 0, acc, lane);
        float t = temperature[0];
        float l0 = fusion_logits[0] / t, l1 = fusion_logits[1] / t;
        float mx = fmaxf(l0, l1);
        float ee0 = __expf(l0 - mx), ee1 = __expf(l1 - mx);
        float w0 = ee0 / (ee0 + ee1), w1 = 1.0f - w0;
        #pragma unroll
        for (int nt = 0; nt < 8; ++nt)
            #pragma unroll
            for (int r = 0; r < 4; ++r) {
                int off = (quad * 4 + r) * 136 + nt * 16 + l16;
                float fp = bf2f(b2[off]);
                b1[off] = f2bf(w0 * acc[nt][r] + w1 * fp);
            }
    }

    // ---- classifier: fused @ Wc1 + bc1 ; LN ; ReLU ; logits ----
    float accH[4][4];
    gemm_ks<4, 4>(b1, 136, ws + OFF_Wc1, bc1, 0, accH, lane);
    #pragma unroll
    for (int r = 0; r < 4; ++r) {
        float s = 0.f, ss = 0.f;
        #pragma unroll
        for (int nt = 0; nt < 4; ++nt) { float x = accH[nt][r]; s += x; ss = fmaf(x, x, ss); }
        s = rowsum16(s); ss = rowsum16(ss);
        float m = s * (1.f / 64.f);
        meanS[r] = m;
        rstdS[r] = rsqrtf(ss * (1.f / 64.f) - m * m + EPS);
    }
    #pragma unroll
    for (int nt = 0; nt < 4; ++nt) {
        float g = gc[nt * 16 + l16], bb = bgc[nt * 16 + l16];
        #pragma unroll
        for (int r = 0; r < 4; ++r) {
            float x = (accH[nt][r] - meanS[r]) * rstdS[r] * g + bb;
            accH[nt][r] = fmaxf(x, 0.0f);
        }
    }
    {
        float w2v[4][2];
        #pragma unroll
        for (int nt = 0; nt < 4; ++nt) {
            float2 w = *(const float2*)&Wc2[(nt * 16 + l16) * 2];
            w2v[nt][0] = w.x; w2v[nt][1] = w.y;
        }
        float o0c = bc2[0], o1c = bc2[1];
        #pragma unroll
        for (int r = 0; r < 4; ++r) {
            float p0 = 0.f, p1 = 0.f;
            #pragma unroll
            for (int nt = 0; nt < 4; ++nt) {
                float hv = accH[nt][r];
                p0 = fmaf(hv, w2v[nt][0], p0);
                p1 = fmaf(hv, w2v[nt][1], p1);
            }
            p0 = rowsum16(p0); p1 = rowsum16(p1);
            if (l16 == 0) {
                int row = rowbase + quad * 4 + r;
                float2 o; o.x = p0 + o0c; o.y = p1 + o1c;
                *(float2*)&out[row * 2] = o;
            }
        }
    }
}

extern "C" void kernel_launch(void* const* d_in, const int* in_sizes, int n_in,
                              void* d_out, int out_size, void* d_ws, size_t ws_size,
                              hipStream_t stream) {
    const float* eeg  = (const float*)d_in[0];
    const float* fmri = (const float*)d_in[1];
    const float* We   = (const float*)d_in[2];
    const float* be   = (const float*)d_in[3];
    const float* ge   = (const float*)d_in[4];
    const float* bge  = (const float*)d_in[5];
    const float* Wf   = (const float*)d_in[6];
    const float* bf   = (const float*)d_in[7];
    const float* gf   = (const float*)d_in[8];
    const float* bgf  = (const float*)d_in[9];
    const float* Wq   = (const float*)d_in[10];
    const float* bq   = (const float*)d_in[11];
    const float* Wk   = (const float*)d_in[12];
    const float* bk   = (const float*)d_in[13];
    const float* Wv   = (const float*)d_in[14];
    const float* bv   = (const float*)d_in[15];
    const float* Wo   = (const float*)d_in[16];
    const float* bo   = (const float*)d_in[17];
    const float* fl   = (const float*)d_in[18];
    const float* temp = (const float*)d_in[19];
    const float* Wc1  = (const float*)d_in[20];
    const float* bc1  = (const float*)d_in[21];
    const float* gc   = (const float*)d_in[22];
    const float* bgc  = (const float*)d_in[23];
    const float* Wc2  = (const float*)d_in[24];
    const float* bc2  = (const float*)d_in[25];
    float* out = (float*)d_out;
    ushort_t* ws = (ushort_t*)d_ws;

    hipLaunchKernelGGL(pack_all, dim3((PACK_TOTAL + 255) / 256), dim3(256), 0, stream,
                       We, Wf, Wq, Wk, Wv, Wo, Wc1, ws);

    int B = in_sizes[0] / 128;     // 131072
    int grid = B / 32;             // 4096 blocks x 128 threads (2 waves x 16 rows)
    hipLaunchKernelGGL(fusion_wave, dim3(grid), dim3(128), 0, stream,
                       eeg, fmri, be, ge, bge, bf, gf, bgf,
                       bq, bk, bv, bo, fl, temp, bc1, gc, bgc, Wc2, bc2,
                       ws, out);
}

// Round 7
// 233.810 us; speedup vs baseline: 1.5815x; 1.2579x over previous
//
#include <hip/hip_runtime.h>
#include <math.h>

#define EPS 1e-5f
#define SCALE 0.17677669529663687f   // 1/sqrt(32)

// packed bf16 weight offsets in d_ws (ushort units)
#define OFF_We  0
#define OFF_Wf  16384
#define OFF_Wq  24576
#define OFF_Wk  40960
#define OFF_Wv  57344
#define OFF_Wo  73728
#define OFF_Wc1 90112
#define PACK_TOTAL 98304

// fp32 param block appended after packed weights (float units, offset from ws+PACK_TOTAL)
#define P_BE   0
#define P_GE   128
#define P_BGE  256
#define P_BF   384
#define P_GF   512
#define P_BGF  640
#define P_BQ   768
#define P_BK   896
#define P_BV   1024
#define P_BO   1152
#define P_BC1  1280
#define P_GC   1344
#define P_BGC  1408
#define P_WC2  1472
#define P_MISC 1600
#define PARAM_N 1605

typedef __bf16 bf16x8 __attribute__((ext_vector_type(8)));
typedef float f32x4 __attribute__((ext_vector_type(4)));
typedef unsigned short ushort_t;
typedef unsigned short ushortx4 __attribute__((ext_vector_type(4)));

__device__ __forceinline__ ushort_t f2bf(float x) {
    unsigned u = __builtin_bit_cast(unsigned, x);
    u = (u + 0x7fffu + ((u >> 16) & 1u)) >> 16;   // RNE
    return (ushort_t)u;
}
__device__ __forceinline__ float bf2f(ushort_t v) {
    unsigned u = ((unsigned)v) << 16;
    return __builtin_bit_cast(float, u);
}

// 16-lane (DPP-row) all-lanes sum via row_ror butterfly — VALU pipe, no LDS.
#define DPPADD(x, ctrl) \
    ((x) + __builtin_bit_cast(float, __builtin_amdgcn_update_dpp( \
        __builtin_bit_cast(int, (x)), __builtin_bit_cast(int, (x)), (ctrl), 0xF, 0xF, false)))

__device__ __forceinline__ float rowsum16(float x) {
    x = DPPADD(x, 0x121);   // row_ror:1
    x = DPPADD(x, 0x122);   // row_ror:2
    x = DPPADD(x, 0x124);   // row_ror:4
    x = DPPADD(x, 0x128);   // row_ror:8
    return x;
}

// tanh-form GELU via sigmoid + HW exp; |err| <= ~4e-4 vs exact erf GELU
__device__ __forceinline__ float gelu_fast(float x) {
    float x2 = x * x;
    float u = x * fmaf(0.07135481283f, x2, 1.5957691216f);
    float e = __expf(-u);
    return x * __builtin_amdgcn_rcpf(1.0f + e);
}

// ---------------- pack kernel: bf16 B-fragment weights + fp32 param block ----------------
__global__ __launch_bounds__(256) void pack_all(
    const float* __restrict__ We, const float* __restrict__ Wf,
    const float* __restrict__ Wq, const float* __restrict__ Wk,
    const float* __restrict__ Wv, const float* __restrict__ Wo,
    const float* __restrict__ Wc1,
    const float* __restrict__ be, const float* __restrict__ ge, const float* __restrict__ bge,
    const float* __restrict__ bf, const float* __restrict__ gf, const float* __restrict__ bgf,
    const float* __restrict__ bq, const float* __restrict__ bk, const float* __restrict__ bv,
    const float* __restrict__ bo, const float* __restrict__ bc1, const float* __restrict__ gc,
    const float* __restrict__ bgc, const float* __restrict__ Wc2, const float* __restrict__ bc2,
    const float* __restrict__ fl, const float* __restrict__ temp,
    ushort_t* __restrict__ ws)
{
    int o = blockIdx.x * 256 + threadIdx.x;
    if (o < PACK_TOTAL) {
        const float* W; int K, N, base;
        if (o < OFF_Wf)        { W = We;  K = 128; N = 128; base = OFF_We; }
        else if (o < OFF_Wq)   { W = Wf;  K = 64;  N = 128; base = OFF_Wf; }
        else if (o < OFF_Wk)   { W = Wq;  K = 128; N = 128; base = OFF_Wq; }
        else if (o < OFF_Wv)   { W = Wk;  K = 128; N = 128; base = OFF_Wk; }
        else if (o < OFF_Wo)   { W = Wv;  K = 128; N = 128; base = OFF_Wv; }
        else if (o < OFF_Wc1)  { W = Wo;  K = 128; N = 128; base = OFF_Wo; }
        else                   { W = Wc1; K = 128; N = 64;  base = OFF_Wc1; }
        int e = o - base;
        int j = e & 7, l = (e >> 3) & 63, rest = e >> 9;
        int KS = K >> 5;
        int s = rest % KS, t = rest / KS;
        int k = s * 32 + ((l >> 4) << 3) + j;
        int n = (t << 4) + (l & 15);
        ws[o] = f2bf(W[k * N + n]);
        return;
    }
    int p = o - PACK_TOTAL;
    if (p >= PARAM_N) return;
    float* wsf = (float*)(ws + PACK_TOTAL);
    float v;
    if (p < 128)        v = be[p];
    else if (p < 256)   v = ge[p - 128];
    else if (p < 384)   v = bge[p - 256];
    else if (p < 512)   v = bf[p - 384];
    else if (p < 640)   v = gf[p - 512];
    else if (p < 768)   v = bgf[p - 640];
    else if (p < 896)   v = bq[p - 768];
    else if (p < 1024)  v = bk[p - 896];
    else if (p < 1152)  v = bv[p - 1024];
    else if (p < 1280)  v = bo[p - 1152];
    else if (p < 1344)  v = bc1[p - 1280];
    else if (p < 1408)  v = gc[p - 1344];
    else if (p < 1472)  v = bgc[p - 1408];
    else if (p < 1600)  v = Wc2[p - 1472];
    else if (p == 1600) v = bc2[0];
    else if (p == 1601) v = bc2[1];
    else if (p == 1602) v = fl[0];
    else if (p == 1603) v = fl[1];
    else                v = temp[0];
    wsf[p] = v;
}

// ---------------- GEMM helpers (A in regs, B from LDS sW, bias from LDS sP) ----------------
template<int KS>
__device__ __forceinline__ void load_af(bf16x8 af[KS], const ushort_t* A, int lane)
{
    const int quad = lane >> 4, l16 = lane & 15;
    #pragma unroll
    for (int ks = 0; ks < KS; ++ks)
        af[ks] = *(const bf16x8*)(A + l16 * 136 + ks * 32 + quad * 8);
}

template<int KS, int NTN>
__device__ __forceinline__ void mma_lds(const bf16x8 af[KS],
    const ushort_t* sW, const float* sB, int nt0, float acc[NTN][4], int lane)
{
    const int l16 = lane & 15;
    #pragma unroll
    for (int t = 0; t < NTN; ++t) {
        float b = sB[(nt0 + t) * 16 + l16];
        f32x4 a0 = {b, b, b, b};
        #pragma unroll
        for (int ks = 0; ks < KS; ++ks) {
            bf16x8 bb = *(const bf16x8*)(sW + (((nt0 + t) * KS + ks) * 64 + lane) * 8);
            a0 = __builtin_amdgcn_mfma_f32_16x16x32_bf16(af[ks], bb, a0, 0, 0, 0);
        }
        #pragma unroll
        for (int r = 0; r < 4; ++r) acc[t][r] = a0[r];
    }
}

// ---------------- main kernel: 4 waves x 16 wave-private rows, LDS-staged weights ----------------
__global__ __launch_bounds__(256, 2) void fusion_stage(
    const float* __restrict__ eeg, const float* __restrict__ fmri,
    const ushort_t* __restrict__ ws, float* __restrict__ out)
{
    __shared__ __align__(16) ushort_t sW[16384];        // 32 KB weight stage buffer
    __shared__ __align__(16) float sP[1664];            // params
    __shared__ __align__(16) ushort_t B1[4][16 * 136];  // per-wave: eeg->ep->ctx->fused
    __shared__ __align__(16) ushort_t B2[4][16 * 136];  // per-wave: fmri->fp

    const int tid = threadIdx.x;
    const int wave = tid >> 6, lane = tid & 63;
    const int quad = lane >> 4, l16 = lane & 15;
    const int rowbase = blockIdx.x * 64 + wave * 16;
    ushort_t* b1 = B1[wave];
    ushort_t* b2 = B2[wave];

    // ---- params -> LDS (visibility guaranteed by stage 1's post-copy barrier) ----
    {
        const float* src = (const float*)(ws + PACK_TOTAL);
        for (int i = tid; i < PARAM_N; i += 256) sP[i] = src[i];
    }

    // ---- stage raw inputs -> bf16 A-layout LDS (wave-private) ----
    {
        const float4* src = (const float4*)(eeg + (size_t)rowbase * 128);
        #pragma unroll
        for (int i = 0; i < 8; ++i) {
            int idx = i * 64 + lane;               // 512 float4 = 16 rows x 32
            float4 v = src[idx];
            int r = idx >> 5, k4 = (idx & 31) * 4;
            *(ushortx4*)&b1[r * 136 + k4] =
                (ushortx4){f2bf(v.x), f2bf(v.y), f2bf(v.z), f2bf(v.w)};
        }
        const float4* srcf = (const float4*)(fmri + (size_t)rowbase * 64);
        #pragma unroll
        for (int i = 0; i < 4; ++i) {
            int idx = i * 64 + lane;               // 256 float4 = 16 rows x 16
            float4 v = srcf[idx];
            int r = idx >> 4, k4 = (idx & 15) * 4;
            *(ushortx4*)&b2[r * 136 + k4] =
                (ushortx4){f2bf(v.x), f2bf(v.y), f2bf(v.z), f2bf(v.w)};
        }
    }

    // cooperative stage copy: barrier(prev consumed) ; copy ; barrier(ready)
    auto stageW = [&](int offU, int nUsh) {
        __syncthreads();
        const uint4* g = (const uint4*)(ws + offU);
        uint4* d = (uint4*)sW;
        int n16 = nUsh >> 3;
        for (int i = tid; i < n16; i += 256) d[i] = g[i];
        __syncthreads();
    };

    float meanS[4], rstdS[4];

    // ---- S1: eeg @ We + be ; LN ; GELU -> ep (b1) ----
    stageW(OFF_We, 16384);
    {
        bf16x8 afR[4]; load_af<4>(afR, b1, lane);
        float acc[8][4];
        mma_lds<4, 8>(afR, sW, sP + P_BE, 0, acc, lane);
        #pragma unroll
        for (int r = 0; r < 4; ++r) {
            float s = 0.f, ss = 0.f;
            #pragma unroll
            for (int nt = 0; nt < 8; ++nt) { float x = acc[nt][r]; s += x; ss = fmaf(x, x, ss); }
            s = rowsum16(s); ss = rowsum16(ss);
            float m = s * (1.f / 128.f);
            meanS[r] = m;
            rstdS[r] = rsqrtf(ss * (1.f / 128.f) - m * m + EPS);
        }
        #pragma unroll
        for (int nt = 0; nt < 8; ++nt) {
            float g = sP[P_GE + nt * 16 + l16], bb = sP[P_BGE + nt * 16 + l16];
            #pragma unroll
            for (int r = 0; r < 4; ++r) {
                float x = (acc[nt][r] - meanS[r]) * rstdS[r] * g + bb;
                b1[(quad * 4 + r) * 136 + nt * 16 + l16] = f2bf(gelu_fast(x));
            }
        }
    }

    // ---- S2: fmri @ Wf + bf ; LN ; GELU -> fp (b2) ----
    stageW(OFF_Wf, 8192);
    {
        bf16x8 afR[2]; load_af<2>(afR, b2, lane);
        float acc[8][4];
        mma_lds<2, 8>(afR, sW, sP + P_BF, 0, acc, lane);
        #pragma unroll
        for (int r = 0; r < 4; ++r) {
            float s = 0.f, ss = 0.f;
            #pragma unroll
            for (int nt = 0; nt < 8; ++nt) { float x = acc[nt][r]; s += x; ss = fmaf(x, x, ss); }
            s = rowsum16(s); ss = rowsum16(ss);
            float m = s * (1.f / 128.f);
            meanS[r] = m;
            rstdS[r] = rsqrtf(ss * (1.f / 128.f) - m * m + EPS);
        }
        #pragma unroll
        for (int nt = 0; nt < 8; ++nt) {
            float g = sP[P_GF + nt * 16 + l16], bb = sP[P_BGF + nt * 16 + l16];
            #pragma unroll
            for (int r = 0; r < 4; ++r) {
                float x = (acc[nt][r] - meanS[r]) * rstdS[r] * g + bb;
                b2[(quad * 4 + r) * 136 + nt * 16 + l16] = f2bf(gelu_fast(x));
            }
        }
    }

    // persistent A-fragments for attention: ep (b1) and fp (b2)
    bf16x8 afE[4]; load_af<4>(afE, b1, lane);
    bf16x8 afF[4]; load_af<4>(afF, b2, lane);

    // ---- S3: q = ep @ Wq + bq (held in regs) ----
    stageW(OFF_Wq, 16384);
    float q[8][4];
    mma_lds<4, 8>(afE, sW, sP + P_BQ, 0, q, lane);

    // ---- S4: KE/KF fused single Wk pass; fold score accumulation ----
    stageW(OFF_Wk, 16384);
    float a0v[4][4];
    {
        float p0a[4][4], p1a[4][4];
        #pragma unroll
        for (int h = 0; h < 4; ++h)
            #pragma unroll
            for (int r = 0; r < 4; ++r) { p0a[h][r] = 0.f; p1a[h][r] = 0.f; }
        #pragma unroll
        for (int nt = 0; nt < 8; ++nt) {
            float b = sP[P_BK + nt * 16 + l16];
            f32x4 e = {b, b, b, b}, f = {b, b, b, b};
            #pragma unroll
            for (int ks = 0; ks < 4; ++ks) {
                bf16x8 bb = *(const bf16x8*)(sW + ((nt * 4 + ks) * 64 + lane) * 8);
                e = __builtin_amdgcn_mfma_f32_16x16x32_bf16(afE[ks], bb, e, 0, 0, 0);
                f = __builtin_amdgcn_mfma_f32_16x16x32_bf16(afF[ks], bb, f, 0, 0, 0);
            }
            int h = nt >> 1;
            #pragma unroll
            for (int r = 0; r < 4; ++r) {
                p0a[h][r] = fmaf(q[nt][r], e[r], p0a[h][r]);
                p1a[h][r] = fmaf(q[nt][r], f[r], p1a[h][r]);
            }
        }
        #pragma unroll
        for (int h = 0; h < 4; ++h)
            #pragma unroll
            for (int r = 0; r < 4; ++r) {
                float p0 = rowsum16(p0a[h][r]);
                float p1 = rowsum16(p1a[h][r]);
                float s0 = p0 * SCALE, s1 = p1 * SCALE;
                float mx = fmaxf(s0, s1);
                float e0 = __expf(s0 - mx), e1 = __expf(s1 - mx);
                a0v[h][r] = e0 * __builtin_amdgcn_rcpf(e0 + e1);
            }
    }

    // ---- S5: ctx = a0*(ep@Wv) + (1-a0)*(fp@Wv) + bv -> b1 (bf16) ----
    stageW(OFF_Wv, 16384);
    #pragma unroll
    for (int nt = 0; nt < 8; ++nt) {
        float b = sP[P_BV + nt * 16 + l16];
        f32x4 e = {b, b, b, b}, f = {b, b, b, b};
        #pragma unroll
        for (int ks = 0; ks < 4; ++ks) {
            bf16x8 bb = *(const bf16x8*)(sW + ((nt * 4 + ks) * 64 + lane) * 8);
            e = __builtin_amdgcn_mfma_f32_16x16x32_bf16(afE[ks], bb, e, 0, 0, 0);
            f = __builtin_amdgcn_mfma_f32_16x16x32_bf16(afF[ks], bb, f, 0, 0, 0);
        }
        int h = nt >> 1;
        #pragma unroll
        for (int r = 0; r < 4; ++r) {
            float a0 = a0v[h][r];
            float c0 = a0 * e[r] + (1.0f - a0) * f[r];
            b1[(quad * 4 + r) * 136 + nt * 16 + l16] = f2bf(c0);
        }
    }

    // ---- S6: eeg_enh = ctx @ Wo + bo ; learned fusion with fp ; fused -> b1 ----
    stageW(OFF_Wo, 16384);
    {
        bf16x8 afC[4]; load_af<4>(afC, b1, lane);
        float acc[8][4];
        mma_lds<4, 8>(afC, sW, sP + P_BO, 0, acc, lane);
        float t = sP[P_MISC + 4];
        float l0 = sP[P_MISC + 2] / t, l1 = sP[P_MISC + 3] / t;
        float mx = fmaxf(l0, l1);
        float ee0 = __expf(l0 - mx), ee1 = __expf(l1 - mx);
        float w0 = ee0 / (ee0 + ee1), w1 = 1.0f - w0;
        #pragma unroll
        for (int nt = 0; nt < 8; ++nt)
            #pragma unroll
            for (int r = 0; r < 4; ++r) {
                int off = (quad * 4 + r) * 136 + nt * 16 + l16;
                float fp = bf2f(b2[off]);
                b1[off] = f2bf(w0 * acc[nt][r] + w1 * fp);
            }
    }

    // ---- S7: classifier: fused @ Wc1 + bc1 ; LN ; ReLU ; logits ----
    stageW(OFF_Wc1, 8192);
    {
        bf16x8 afU[4]; load_af<4>(afU, b1, lane);
        float accH[4][4];
        mma_lds<4, 4>(afU, sW, sP + P_BC1, 0, accH, lane);
        #pragma unroll
        for (int r = 0; r < 4; ++r) {
            float s = 0.f, ss = 0.f;
            #pragma unroll
            for (int nt = 0; nt < 4; ++nt) { float x = accH[nt][r]; s += x; ss = fmaf(x, x, ss); }
            s = rowsum16(s); ss = rowsum16(ss);
            float m = s * (1.f / 64.f);
            meanS[r] = m;
            rstdS[r] = rsqrtf(ss * (1.f / 64.f) - m * m + EPS);
        }
        #pragma unroll
        for (int nt = 0; nt < 4; ++nt) {
            float g = sP[P_GC + nt * 16 + l16], bb = sP[P_BGC + nt * 16 + l16];
            #pragma unroll
            for (int r = 0; r < 4; ++r) {
                float x = (accH[nt][r] - meanS[r]) * rstdS[r] * g + bb;
                accH[nt][r] = fmaxf(x, 0.0f);
            }
        }
        float w2v[4][2];
        #pragma unroll
        for (int nt = 0; nt < 4; ++nt) {
            float2 w = *(const float2*)&sP[P_WC2 + (nt * 16 + l16) * 2];
            w2v[nt][0] = w.x; w2v[nt][1] = w.y;
        }
        float o0c = sP[P_MISC + 0], o1c = sP[P_MISC + 1];
        #pragma unroll
        for (int r = 0; r < 4; ++r) {
            float p0 = 0.f, p1 = 0.f;
            #pragma unroll
            for (int nt = 0; nt < 4; ++nt) {
                float hv = accH[nt][r];
                p0 = fmaf(hv, w2v[nt][0], p0);
                p1 = fmaf(hv, w2v[nt][1], p1);
            }
            p0 = rowsum16(p0); p1 = rowsum16(p1);
            if (l16 == 0) {
                int row = rowbase + quad * 4 + r;
                float2 o; o.x = p0 + o0c; o.y = p1 + o1c;
                *(float2*)&out[row * 2] = o;
            }
        }
    }
}

extern "C" void kernel_launch(void* const* d_in, const int* in_sizes, int n_in,
                              void* d_out, int out_size, void* d_ws, size_t ws_size,
                              hipStream_t stream) {
    const float* eeg  = (const float*)d_in[0];
    const float* fmri = (const float*)d_in[1];
    const float* We   = (const float*)d_in[2];
    const float* be   = (const float*)d_in[3];
    const float* ge   = (const float*)d_in[4];
    const float* bge  = (const float*)d_in[5];
    const float* Wf   = (const float*)d_in[6];
    const float* bf   = (const float*)d_in[7];
    const float* gf   = (const float*)d_in[8];
    const float* bgf  = (const float*)d_in[9];
    const float* Wq   = (const float*)d_in[10];
    const float* bq   = (const float*)d_in[11];
    const float* Wk   = (const float*)d_in[12];
    const float* bk   = (const float*)d_in[13];
    const float* Wv   = (const float*)d_in[14];
    const float* bv   = (const float*)d_in[15];
    const float* Wo   = (const float*)d_in[16];
    const float* bo   = (const float*)d_in[17];
    const float* fl   = (const float*)d_in[18];
    const float* temp = (const float*)d_in[19];
    const float* Wc1  = (const float*)d_in[20];
    const float* bc1  = (const float*)d_in[21];
    const float* gc   = (const float*)d_in[22];
    const float* bgc  = (const float*)d_in[23];
    const float* Wc2  = (const float*)d_in[24];
    const float* bc2  = (const float*)d_in[25];
    float* out = (float*)d_out;
    ushort_t* ws = (ushort_t*)d_ws;

    int packThreads = PACK_TOTAL + 2048;
    hipLaunchKernelGGL(pack_all, dim3((packThreads + 255) / 256), dim3(256), 0, stream,
                       We, Wf, Wq, Wk, Wv, Wo, Wc1,
                       be, ge, bge, bf, gf, bgf, bq, bk, bv, bo,
                       bc1, gc, bgc, Wc2, bc2, fl, temp, ws);

    int B = in_sizes[0] / 128;     // 131072
    int grid = B / 64;             // 2048 blocks x 256 threads (4 waves x 16 rows)
    hipLaunchKernelGGL(fusion_stage, dim3(grid), dim3(256), 0, stream,
                       eeg, fmri, ws, out);
}